// Round 8
// baseline (5150.987 us; speedup 1.0000x reference)
//
#include <hip/hip_runtime.h>

#define BB 4
#define LL 2048
#define QQ 2048
#define HH 16
#define DD 64
#define EE 1024
#define NB 512

// ================= naive tiled fp32 GEMMs (correctness-first diagnostic) =================

// C[m,n] = sum_k A[m,k] * B[n,k]   (A: M x K row-major, B: N x K row-major)
__global__ __launch_bounds__(256) void nb_gemm_nt(
    const float* __restrict__ A, const float* __restrict__ B, float* __restrict__ C,
    int M, int N, int K)
{
  __shared__ float As[32][33], Bs[32][33];
  const int tid = threadIdx.x;
  const int tx = tid & 15, ty = tid >> 4;
  const int m0 = blockIdx.y * 32, n0 = blockIdx.x * 32;
  float acc00 = 0.f, acc01 = 0.f, acc10 = 0.f, acc11 = 0.f;
  for (int k0 = 0; k0 < K; k0 += 32) {
    for (int i = tid; i < 1024; i += 256) {
      int r = i >> 5, c = i & 31;
      As[r][c] = A[(long)(m0 + r) * K + k0 + c];
      Bs[r][c] = B[(long)(n0 + r) * K + k0 + c];
    }
    __syncthreads();
    #pragma unroll 8
    for (int kk = 0; kk < 32; kk++) {
      float a0 = As[ty*2][kk],   a1 = As[ty*2+1][kk];
      float b0 = Bs[tx*2][kk],   b1 = Bs[tx*2+1][kk];
      acc00 += a0*b0; acc01 += a0*b1; acc10 += a1*b0; acc11 += a1*b1;
    }
    __syncthreads();
  }
  C[(long)(m0 + ty*2    ) * N + n0 + tx*2    ] = acc00;
  C[(long)(m0 + ty*2    ) * N + n0 + tx*2 + 1] = acc01;
  C[(long)(m0 + ty*2 + 1) * N + n0 + tx*2    ] = acc10;
  C[(long)(m0 + ty*2 + 1) * N + n0 + tx*2 + 1] = acc11;
}

// C[m,n] = sum_k A[k,m] * B[k,n]   (A: K x M row-major, B: K x N row-major)
__global__ __launch_bounds__(256) void nb_gemm_tn(
    const float* __restrict__ A, const float* __restrict__ B, float* __restrict__ C,
    int M, int N, int K)
{
  __shared__ float As[32][33], Bs[32][33];   // [kk][mm] / [kk][nn]
  const int tid = threadIdx.x;
  const int tx = tid & 15, ty = tid >> 4;
  const int m0 = blockIdx.y * 32, n0 = blockIdx.x * 32;
  float acc00 = 0.f, acc01 = 0.f, acc10 = 0.f, acc11 = 0.f;
  for (int k0 = 0; k0 < K; k0 += 32) {
    for (int i = tid; i < 1024; i += 256) {
      int r = i >> 5, c = i & 31;
      As[r][c] = A[(long)(k0 + r) * M + m0 + c];
      Bs[r][c] = B[(long)(k0 + r) * N + n0 + c];
    }
    __syncthreads();
    #pragma unroll 8
    for (int kk = 0; kk < 32; kk++) {
      float a0 = As[kk][ty*2], a1 = As[kk][ty*2+1];
      float b0 = Bs[kk][tx*2], b1 = Bs[kk][tx*2+1];
      acc00 += a0*b0; acc01 += a0*b1; acc10 += a1*b0; acc11 += a1*b1;
    }
    __syncthreads();
  }
  C[(long)(m0 + ty*2    ) * N + n0 + tx*2    ] = acc00;
  C[(long)(m0 + ty*2    ) * N + n0 + tx*2 + 1] = acc01;
  C[(long)(m0 + ty*2 + 1) * N + n0 + tx*2    ] = acc10;
  C[(long)(m0 + ty*2 + 1) * N + n0 + tx*2 + 1] = acc11;
}

// ================= scores -> mu_q, sig2 (one block per (q,h), flat layouts) =============
// S[q,n] = (1/8) * sum_d qry[q, h*64+d] * keys[n, h*64+d]
// mu = sigmoid(sum_n S*wmu) ; s2 = max(softplus(sum_n S*wsg), 1e-4)
__global__ __launch_bounds__(256) void nb_scores(
    const float* __restrict__ qry,  const float* __restrict__ keys,
    const float* __restrict__ wmu,  const float* __restrict__ wsg,
    float* __restrict__ muq, float* __restrict__ sg2)
{
  __shared__ float qv[64];
  __shared__ float psm[256], pss[256];
  const int t = threadIdx.x;
  const int qrow = blockIdx.x, h = blockIdx.y;
  if (t < 64) qv[t] = qry[(long)qrow * EE + h * 64 + t];
  __syncthreads();
  float a_mu = 0.f, a_sg = 0.f;
  for (int n = t; n < NB; n += 256) {
    const float* kp = keys + (long)n * EE + h * 64;
    float s = 0.f;
    #pragma unroll 16
    for (int d = 0; d < 64; d++) s += qv[d] * kp[d];
    a_mu += s * wmu[n];
    a_sg += s * wsg[n];
  }
  psm[t] = a_mu; pss[t] = a_sg;
  __syncthreads();
  for (int s = 128; s > 0; s >>= 1) {
    if (t < s) { psm[t] += psm[t + s]; pss[t] += pss[t + s]; }
    __syncthreads();
  }
  if (t == 0) {
    float x = psm[0] * 0.125f;                        // /sqrt(64)
    float mu = 1.f / (1.f + expf(-x));                // sigmoid
    float y = pss[0] * 0.125f;
    float sp = (y > 20.f) ? y : log1pf(expf(y));      // softplus
    muq[(long)h * QQ + qrow] = mu;
    sg2[(long)h * QQ + qrow] = fmaxf(sp, 1e-4f);
  }
}

// ================= ctx (one block per q): r on the fly, flat vals [n][e] ================
// ctx[q, e=(h*64+d)] = sum_n r(h,q,n) * vals[n, e]
// r = exp(-0.5 (mu - bmu_n)^2 / v) / sqrt(2 pi v),  v = s2 + bsg_n^2
__global__ __launch_bounds__(256) void nb_ctx(
    const float* __restrict__ vals, const float* __restrict__ muq, const float* __restrict__ sg2,
    const float* __restrict__ bmu,  const float* __restrict__ bsg, float* __restrict__ ctx)
{
  __shared__ float rbuf[HH * NB];     // 16*512 fp32 = 32 KB
  __shared__ float muh[HH], s2h[HH];
  const int t = threadIdx.x;
  const int qrow = blockIdx.x;
  if (t < HH) {
    muh[t] = muq[(long)t * QQ + qrow];
    s2h[t] = sg2[(long)t * QQ + qrow];
  }
  __syncthreads();
  for (int idx = t; idx < HH * NB; idx += 256) {
    int h = idx >> 9, n = idx & 511;
    float tt = muh[h] - bmu[n];
    float v  = s2h[h] + bsg[n] * bsg[n];
    rbuf[idx] = expf(-0.5f * tt * tt / v) / sqrtf(6.283185307179586f * v);
  }
  __syncthreads();
  #pragma unroll
  for (int i = 0; i < 4; i++) {
    int e = i * 256 + t;
    int h = e >> 6;
    const float* rp = rbuf + h * NB;
    float acc = 0.f;
    for (int n = 0; n < NB; n++) acc += rp[n] * vals[(long)n * EE + e];
    ctx[(long)qrow * EE + e] = acc;
  }
}

extern "C" void kernel_launch(void* const* d_in, const int* in_sizes, int n_in,
                              void* d_out, int out_size, void* d_ws, size_t ws_size,
                              hipStream_t stream) {
  const float* k   = (const float*)d_in[0];
  const float* q   = (const float*)d_in[1];
  const float* Wq  = (const float*)d_in[2];
  const float* Wk  = (const float*)d_in[3];
  const float* Wv  = (const float*)d_in[4];
  const float* Wo  = (const float*)d_in[5];
  const float* wmu = (const float*)d_in[6];
  const float* wsg = (const float*)d_in[7];
  const float* Gs  = (const float*)d_in[8];
  const float* bmu = (const float*)d_in[9];
  const float* bsg = (const float*)d_in[10];
  float* out = (float*)d_out;

  // Per-batch ws overlay: TOTAL 14.5 MiB (defensive vs unknown ws_size).
  //   Bm_b   [0.0, 2.0) MiB   fp32 [512][1024]
  //   keys_b [2.0, 4.0) MiB   fp32 [512][1024] flat (h folded into e)
  //   vals_b [4.0, 6.0) MiB   fp32 [512][1024] flat
  //   muq_b  [6.0, 6.125) MiB fp32 [16][2048]
  //   sg2_b  [6.125,6.25) MiB fp32 [16][2048]
  //   qry_b / ctx_b [6.5, 14.5) MiB fp32 [2048][1024]  (disjoint lifetimes:
  //       qry written st4, read st5; ctx written st6, read st7)
  char* ws = (char*)d_ws;
  float* Bm_b   = (float*)(ws + 0);
  float* keys_b = (float*)(ws + (2u  << 20));
  float* vals_b = (float*)(ws + (4u  << 20));
  float* muq_b  = (float*)(ws + (6u  << 20));
  float* sg2_b  = (float*)(ws + (6u  << 20) + (128u << 10));
  float* qry_b  = (float*)(ws + (6u  << 20) + (512u << 10));
  float* ctx_b  = qry_b;

  for (int b = 0; b < BB; b++) {
    const float* k_b = k + (long)b * LL * EE;
    const float* q_b = q + (long)b * QQ * EE;
    float*       o_b = out + (long)b * QQ * EE;
    // st2: Bm_b[nb][e] = sum_l Gs[l][nb] * k_b[l][e]
    nb_gemm_tn<<<dim3(EE/32, NB/32), 256, 0, stream>>>(Gs, k_b, Bm_b, NB, EE, LL);
    // st3a: keys_b[nb][e] = sum_e' Bm_b[nb][e'] * Wk[e][e']
    nb_gemm_nt<<<dim3(EE/32, NB/32), 256, 0, stream>>>(Bm_b, Wk, keys_b, NB, EE, EE);
    // st3b: vals_b[nb][e] = sum_e' Bm_b[nb][e'] * Wv[e][e']
    nb_gemm_nt<<<dim3(EE/32, NB/32), 256, 0, stream>>>(Bm_b, Wv, vals_b, NB, EE, EE);
    // st4: qry_b[q][e] = sum_e' q_b[q][e'] * Wq[e][e']
    nb_gemm_nt<<<dim3(EE/32, QQ/32), 256, 0, stream>>>(q_b, Wq, qry_b, QQ, EE, EE);
    // st5: mu_q, sig2
    nb_scores<<<dim3(QQ, HH), 256, 0, stream>>>(qry_b, keys_b, wmu, wsg, muq_b, sg2_b);
    // st6: ctx_b[q][e] (overwrites dead qry_b)
    nb_ctx<<<dim3(QQ), 256, 0, stream>>>(vals_b, muq_b, sg2_b, bmu, bsg, ctx_b);
    // st7: out_b[q][e] = sum_e' ctx_b[q][e'] * Wo[e][e']
    nb_gemm_nt<<<dim3(EE/32, QQ/32), 256, 0, stream>>>(ctx_b, Wo, o_b, QQ, EE, EE);
  }
  (void)in_sizes; (void)n_in; (void)out_size; (void)ws_size;
}